// Round 1
// baseline (2816.837 us; speedup 1.0000x reference)
//
#include <hip/hip_runtime.h>
#include <stdint.h>

#define SEQ 1024
#define BATCH 512
#define IN_DIM 128
#define HID 256

typedef _Float16 h2_t __attribute__((ext_vector_type(2)));

__device__ __forceinline__ float dot2(uint32_t a, uint32_t b, float c) {
#if __has_builtin(__builtin_amdgcn_fdot2)
    return __builtin_amdgcn_fdot2(__builtin_bit_cast(h2_t, a),
                                  __builtin_bit_cast(h2_t, b), c, false);
#else
    h2_t ha = __builtin_bit_cast(h2_t, a);
    h2_t hb = __builtin_bit_cast(h2_t, b);
    return c + (float)ha[0] * (float)hb[0] + (float)ha[1] * (float)hb[1];
#endif
}

__device__ __forceinline__ uint16_t f2h(float x) {
    _Float16 h = (_Float16)x;
    return __builtin_bit_cast(uint16_t, h);
}
__device__ __forceinline__ uint32_t pack2(float a, float b) {
    return (uint32_t)f2h(a) | ((uint32_t)f2h(b) << 16);
}

// One block per 2 batch rows, persistent across all SEQ steps.
// thread j (0..255) owns hidden unit j for both rows.
// W_in column + W_hh column live in VGPRs as packed f16 pairs.
// h (f16 pairs) and x-tile (f16 pairs) are double-buffered in LDS.
__launch_bounds__(256, 1)
__global__ void ctrnn_fused(const float* __restrict__ x,
                            const float* __restrict__ h0,
                            const float* __restrict__ Win,
                            const float* __restrict__ bin,
                            const float* __restrict__ Whh,
                            const float* __restrict__ bhh,
                            float* __restrict__ out) {
    const int j  = threadIdx.x;        // hidden index
    const int b0 = blockIdx.x * 2;     // batch rows b0, b0+1

    __shared__ __align__(16) uint32_t XS[2][2][IN_DIM / 2]; // [buf][row][pair] 1 KB
    __shared__ __align__(16) uint32_t HS[2][2][HID / 2];    // [buf][row][pair] 2 KB

    // ---- weights into registers (packed f16 pairs), coalesced loads ----
    uint32_t win[IN_DIM / 2];
#pragma unroll
    for (int kk = 0; kk < IN_DIM / 2; kk++) {
        float w0 = Win[(2 * kk) * HID + j];
        float w1 = Win[(2 * kk + 1) * HID + j];
        win[kk] = pack2(w0, w1);
    }
    uint32_t whh[HID / 2];
#pragma unroll
    for (int kk = 0; kk < HID / 2; kk++) {
        float w0 = Whh[(2 * kk) * HID + j];
        float w1 = Whh[(2 * kk + 1) * HID + j];
        whh[kk] = pack2(w0, w1);
    }
    const float bias = bin[j] + bhh[j];

    // ---- init h (read the actual hidden input; it is zeros per setup) ----
    float hc0 = h0[b0 * HID + j];
    float hc1 = h0[(b0 + 1) * HID + j];
    ((uint16_t*)HS)[0 * HID + j] = f2h(hc0);   // buf0 row0
    ((uint16_t*)HS)[1 * HID + j] = f2h(hc1);   // buf0 row1

    // ---- stage x[0]; prefetch x[1], x[2] ----
    const int row = j >> 7;    // 0 or 1
    const int c   = j & 127;   // input-feature index
    {
        float v = x[(0 * BATCH + b0 + row) * IN_DIM + c];
        ((uint16_t*)XS)[(0 * 2 + row) * IN_DIM + c] = f2h(v);
    }
    float xv_ready = x[(1 * BATCH + b0 + row) * IN_DIM + c]; // x[s+1] to stage
    float xv_fly   = x[(2 * BATCH + b0 + row) * IN_DIM + c]; // x[s+2] in flight
    __syncthreads();

    for (int s = 0; s < SEQ; s++) {
        const int cur = s & 1;
        const int nxt = cur ^ 1;

        // stage x[s+1] into the "next" buffer; rotate prefetch queue
        ((uint16_t*)XS)[(nxt * 2 + row) * IN_DIM + c] = f2h(xv_ready);
        xv_ready = xv_fly;
        const int sl = (s + 3 < SEQ) ? (s + 3) : (SEQ - 1);
        xv_fly = x[(sl * BATCH + b0 + row) * IN_DIM + c];

        float acc0 = bias, acc1 = bias;

        // input projection: x[s] dot W_in[:, j]
        const uint4* xc0 = (const uint4*)&XS[cur][0][0];
        const uint4* xc1 = (const uint4*)&XS[cur][1][0];
#pragma unroll
        for (int q = 0; q < IN_DIM / 8; q++) {  // 16
            uint4 xa = xc0[q];
            uint4 xb = xc1[q];
            acc0 = dot2(xa.x, win[4 * q + 0], acc0);
            acc0 = dot2(xa.y, win[4 * q + 1], acc0);
            acc0 = dot2(xa.z, win[4 * q + 2], acc0);
            acc0 = dot2(xa.w, win[4 * q + 3], acc0);
            acc1 = dot2(xb.x, win[4 * q + 0], acc1);
            acc1 = dot2(xb.y, win[4 * q + 1], acc1);
            acc1 = dot2(xb.z, win[4 * q + 2], acc1);
            acc1 = dot2(xb.w, win[4 * q + 3], acc1);
        }

        // recurrent projection: h dot W_hh[:, j]
        const uint4* ha_p = (const uint4*)&HS[cur][0][0];
        const uint4* hb_p = (const uint4*)&HS[cur][1][0];
#pragma unroll
        for (int q = 0; q < HID / 8; q++) {     // 32
            uint4 ha = ha_p[q];
            uint4 hb = hb_p[q];
            acc0 = dot2(ha.x, whh[4 * q + 0], acc0);
            acc0 = dot2(ha.y, whh[4 * q + 1], acc0);
            acc0 = dot2(ha.z, whh[4 * q + 2], acc0);
            acc0 = dot2(ha.w, whh[4 * q + 3], acc0);
            acc1 = dot2(hb.x, whh[4 * q + 0], acc1);
            acc1 = dot2(hb.y, whh[4 * q + 1], acc1);
            acc1 = dot2(hb.z, whh[4 * q + 2], acc1);
            acc1 = dot2(hb.w, whh[4 * q + 3], acc1);
        }

        // h_new = 0.8*h + 0.2*relu(pre)
        float hn0 = 0.8f * hc0 + 0.2f * fmaxf(acc0, 0.0f);
        float hn1 = 0.8f * hc1 + 0.2f * fmaxf(acc1, 0.0f);

        out[((size_t)s * BATCH + b0) * HID + j]     = hn0;
        out[((size_t)s * BATCH + b0 + 1) * HID + j] = hn1;

        ((uint16_t*)HS)[(nxt * 2 + 0) * HID + j] = f2h(hn0);
        ((uint16_t*)HS)[(nxt * 2 + 1) * HID + j] = f2h(hn1);
        hc0 = hn0;
        hc1 = hn1;
        __syncthreads();
    }

    // h_last
    float* hl = out + (size_t)SEQ * BATCH * HID;
    hl[b0 * HID + j]       = hc0;
    hl[(b0 + 1) * HID + j] = hc1;
}

extern "C" void kernel_launch(void* const* d_in, const int* in_sizes, int n_in,
                              void* d_out, int out_size, void* d_ws, size_t ws_size,
                              hipStream_t stream) {
    const float* x   = (const float*)d_in[0];  // [SEQ, BATCH, IN]
    const float* h0  = (const float*)d_in[1];  // [BATCH, HID]
    const float* Win = (const float*)d_in[2];  // [IN, HID]
    const float* bin = (const float*)d_in[3];  // [HID]
    const float* Whh = (const float*)d_in[4];  // [HID, HID]
    const float* bhh = (const float*)d_in[5];  // [HID]
    float* out = (float*)d_out;                // [SEQ,BATCH,HID] then [BATCH,HID]

    ctrnn_fused<<<BATCH / 2, HID, 0, stream>>>(x, h0, Win, bin, Whh, bhh, out);
}